// Round 1
// baseline (1106.341 us; speedup 1.0000x reference)
//
#include <hip/hip_runtime.h>
#include <hip/hip_bf16.h>
#include <hip/hip_fp16.h>
#include <math.h>

#define BDIM 2
#define NDIM 4096
#define CDIM 128
#define NP   4097          // NDIM + 1 (dustbin)
#define LDE  4104          // leading dim of E, multiple of 8 for 16B-aligned rows
#define NCH  33            // row chunks for column pass (33*128 >= 4097)
#define CHROWS 128
#define TOPK 8

typedef __attribute__((ext_vector_type(8))) short short8;
typedef __attribute__((ext_vector_type(4))) float f32x4;

// -------- block reduce (256 threads = 4 waves), valid on thread 0 --------
__device__ __forceinline__ float block_reduce_sum(float v) {
    __shared__ float sh[4];
    int lane = threadIdx.x & 63, wv = threadIdx.x >> 6;
    #pragma unroll
    for (int o = 32; o > 0; o >>= 1) v += __shfl_xor(v, o);
    __syncthreads();
    if (lane == 0) sh[wv] = v;
    __syncthreads();
    float r = 0.f;
    if (threadIdx.x == 0) r = sh[0] + sh[1] + sh[2] + sh[3];
    return r;
}

// -------- 1. L2-normalize rows, write bf16 --------
__global__ __launch_bounds__(64) void knorm(const float* __restrict__ feat,
                                            __hip_bfloat16* __restrict__ out) {
    int row = blockIdx.x;               // BDIM*NDIM rows
    int t = threadIdx.x;                // 64 threads, 2 elems each
    const float2 x = ((const float2*)(feat + (size_t)row * CDIM))[t];
    float s = x.x * x.x + x.y * x.y;
    #pragma unroll
    for (int o = 32; o > 0; o >>= 1) s += __shfl_xor(s, o);
    float inv = 1.f / fmaxf(sqrtf(s), 1e-12f);
    __hip_bfloat16* o2 = out + (size_t)row * CDIM;
    o2[2 * t]     = __float2bfloat16(x.x * inv);
    o2[2 * t + 1] = __float2bfloat16(x.y * inv);
}

// -------- 2. scores GEMM (MFMA bf16) -> E = exp(clip(scores/temp)) fp16 --------
__global__ __launch_bounds__(256) void kgemm(const __hip_bfloat16* __restrict__ A16,
                                             const __hip_bfloat16* __restrict__ B16,
                                             __half* __restrict__ E,
                                             const float* __restrict__ tmpp) {
    int b = blockIdx.z;
    int i0 = blockIdx.y * 128, j0 = blockIdx.x * 128;
    int tid = threadIdx.x, lane = tid & 63, wv = tid >> 6;
    int wr = wv >> 1, wc = wv & 1;                 // 2x2 waves, 64x64 tile each
    const unsigned short* Ab = (const unsigned short*)A16 + (size_t)b * NDIM * CDIM;
    const unsigned short* Bb = (const unsigned short*)B16 + (size_t)b * NDIM * CDIM;
    int ar = i0 + wr * 64 + (lane & 15);
    int br = j0 + wc * 64 + (lane & 15);
    int koff = (lane >> 4) * 8;
    f32x4 acc[4][4] = {};
    for (int k0 = 0; k0 < CDIM; k0 += 32) {
        short8 a[4], bb[4];
        #pragma unroll
        for (int m = 0; m < 4; m++)
            a[m] = *(const short8*)(Ab + (size_t)(ar + m * 16) * CDIM + k0 + koff);
        #pragma unroll
        for (int n = 0; n < 4; n++)
            bb[n] = *(const short8*)(Bb + (size_t)(br + n * 16) * CDIM + k0 + koff);
        #pragma unroll
        for (int m = 0; m < 4; m++)
            #pragma unroll
            for (int n = 0; n < 4; n++)
                acc[m][n] = __builtin_amdgcn_mfma_f32_16x16x32_bf16(a[m], bb[n], acc[m][n], 0, 0, 0);
    }
    float temp = *tmpp;                 // reference divides by RAW temp here
    size_t ebase = (size_t)b * NP * LDE;
    int orow0 = (lane >> 4) * 4;
    int ocol = lane & 15;
    #pragma unroll
    for (int m = 0; m < 4; m++)
        #pragma unroll
        for (int n = 0; n < 4; n++) {
            int gj = j0 + wc * 64 + n * 16 + ocol;
            #pragma unroll
            for (int q = 0; q < 4; q++) {
                int gi = i0 + wr * 64 + m * 16 + orow0 + q;
                float s = acc[m][n][q] / temp;
                if (s != s) s = 0.f;                       // nan_to_num
                s = fminf(fmaxf(s, -50.f), 50.f);          // clip
                float e = fminf(expf(s), 60000.f);         // fp16-safe
                E[ebase + (size_t)gi * LDE + gj] = __float2half(e);
            }
        }
}

// -------- 3. dustbin row/col/corner --------
__global__ void kdust(__half* __restrict__ E, const float* __restrict__ dsp,
                      const float* __restrict__ tmpp) {
    int t = blockIdx.x * 256 + threadIdx.x;
    float temp = fminf(fmaxf(*tmpp, 0.2f), 10.f);
    float ds = fminf(fmaxf((*dsp) / temp, -50.f), 50.f);
    __half e = __float2half(fminf(expf(ds), 60000.f));
    if (t < BDIM * NDIM) {
        int b = t / NDIM, j = t % NDIM;
        E[((size_t)b * NP + NDIM) * LDE + j] = e;          // dust row
    } else if (t < 2 * BDIM * NDIM) {
        int u2 = t - BDIM * NDIM;
        int b = u2 / NDIM, i = u2 % NDIM;
        E[((size_t)b * NP + i) * LDE + NDIM] = e;          // dust col
    } else if (t < 2 * BDIM * NDIM + BDIM) {
        int b = t - 2 * BDIM * NDIM;
        E[((size_t)b * NP + NDIM) * LDE + NDIM] = __float2half(1.f);  // corner exp(0)
    }
}

__global__ void kinitw(float* __restrict__ w) {
    int t = blockIdx.x * 256 + threadIdx.x;
    if (t < BDIM * NP) w[t] = 1.f;     // v = 0 -> e^v = 1
}

// -------- 4a. row pass: r_i = sum_j E_ij * w_j ; xu_i = mu_i / r_i --------
__global__ __launch_bounds__(256) void krow(const __half* __restrict__ E,
                                            const float* __restrict__ w,
                                            float* __restrict__ xu) {
    int b = blockIdx.y, i = blockIdx.x;   // i < NP
    const unsigned short* row = (const unsigned short*)E + ((size_t)b * NP + i) * LDE;
    const float* wb = w + (size_t)b * NP;
    float acc = 0.f;
    for (int j8 = threadIdx.x; j8 < 513; j8 += 256) {
        int j = j8 * 8;
        if (j8 < 512) {
            short8 raw = *(const short8*)(row + j);
            float4 w0 = ((const float4*)(wb + j))[0];
            float4 w1 = ((const float4*)(wb + j))[1];
            acc += __half2float(__ushort_as_half((unsigned short)raw[0])) * w0.x;
            acc += __half2float(__ushort_as_half((unsigned short)raw[1])) * w0.y;
            acc += __half2float(__ushort_as_half((unsigned short)raw[2])) * w0.z;
            acc += __half2float(__ushort_as_half((unsigned short)raw[3])) * w0.w;
            acc += __half2float(__ushort_as_half((unsigned short)raw[4])) * w1.x;
            acc += __half2float(__ushort_as_half((unsigned short)raw[5])) * w1.y;
            acc += __half2float(__ushort_as_half((unsigned short)raw[6])) * w1.z;
            acc += __half2float(__ushort_as_half((unsigned short)raw[7])) * w1.w;
        } else if (j < NP) {               // j == 4096 tail
            acc += __half2float(__ushort_as_half(row[j])) * wb[j];
        }
    }
    float tot = block_reduce_sum(acc);
    if (threadIdx.x == 0) {
        float mu = (i == NDIM) ? 0.5f : (1.f / 8192.f);
        xu[(size_t)b * NP + i] = mu / fmaxf(tot, 1e-35f);
    }
}

// -------- 4b. column pass partials: cpart[b][ch][j] = sum_{i in chunk} E_ij * xu_i --------
__global__ __launch_bounds__(256) void kcolp(const __half* __restrict__ E,
                                             const float* __restrict__ xu,
                                             float* __restrict__ cpart) {
    int b = blockIdx.z, ch = blockIdx.y, pan = blockIdx.x;
    int j = pan * 512 + threadIdx.x * 2;
    if (j >= NP) return;
    int r0 = ch * CHROWS, r1 = min(r0 + CHROWS, NP);
    const __half* base = E + (size_t)b * NP * LDE + j;
    const float* xb = xu + (size_t)b * NP;
    float a0 = 0.f, a1 = 0.f;
    for (int i = r0; i < r1; i++) {
        float x = xb[i];
        float2 e2 = __half22float2(*(const __half2*)(base + (size_t)i * LDE));
        a0 += e2.x * x;
        a1 += e2.y * x;
    }
    float* cp = cpart + ((size_t)b * NCH + ch) * LDE;
    cp[j] = a0;
    if (j + 1 < NP) cp[j + 1] = a1;
}

// -------- 4c. finish: w_j = nu_j / sum_ch cpart --------
__global__ void kcolf(const float* __restrict__ cpart, float* __restrict__ w) {
    int t = blockIdx.x * 256 + threadIdx.x;
    if (t >= BDIM * NP) return;
    int b = t / NP, j = t % NP;
    float s = 0.f;
    for (int ch = 0; ch < NCH; ch++) s += cpart[((size_t)b * NCH + ch) * LDE + j];
    float nu = (j == NDIM) ? 0.5f : (1.f / 8192.f);
    w[t] = nu / fmaxf(s, 1e-35f);
}

// -------- 5. final row pass: row mass, expected pos, top-8 (exact tie-break) --------
__global__ __launch_bounds__(256) void kfinal(const __half* __restrict__ E,
                                              const float* __restrict__ xu,
                                              const float* __restrict__ w,
                                              const float* __restrict__ posB,
                                              float* __restrict__ conf,
                                              float* __restrict__ bex,
                                              float* __restrict__ tlogp,
                                              float* __restrict__ tpos) {
    int b = blockIdx.y, i = blockIdx.x;   // i < NDIM
    int tid = threadIdx.x;
    const unsigned short* row = (const unsigned short*)E + ((size_t)b * NP + i) * LDE;
    const float* wb = w + (size_t)b * NP;
    const float2* pb = (const float2*)posB + (size_t)b * NDIM;
    float eu = xu[(size_t)b * NP + i];
    float rs = 0.f, px = 0.f, py = 0.f;
    float tv[TOPK]; int ti[TOPK];
    #pragma unroll
    for (int s = 0; s < TOPK; s++) { tv[s] = -1.f; ti[s] = 0x7fffffff; }
    for (int j8 = tid; j8 < NDIM / 8; j8 += 256) {
        int j = j8 * 8;
        short8 raw = *(const short8*)(row + j);
        #pragma unroll
        for (int e = 0; e < 8; e++) {
            int jj = j + e;
            float p = __half2float(__ushort_as_half((unsigned short)raw[e])) * eu * wb[jj];
            float2 q = pb[jj];
            rs += p; px += p * q.x; py += p * q.y;
            float pv = p; int pj = jj;       // bubble insert, fully static indexing
            #pragma unroll
            for (int s = 0; s < TOPK; s++) {
                bool gt = pv > tv[s];
                float nv = gt ? pv : tv[s]; int ni = gt ? pj : ti[s];
                float ov = gt ? tv[s] : pv; int oi = gt ? ti[s] : pj;
                tv[s] = nv; ti[s] = ni; pv = ov; pj = oi;
            }
        }
    }
    float rst = block_reduce_sum(rs);
    float pxt = block_reduce_sum(px);
    float pyt = block_reduce_sum(py);
    // ---- merge 256x8 candidates, tie-break by smaller index (top_k semantics) ----
    __shared__ float lv[2048]; __shared__ int li[2048];
    __shared__ float rv[256];  __shared__ int ri[256]; __shared__ int ro[256];
    __shared__ float outv[TOPK]; __shared__ int outi[TOPK];
    #pragma unroll
    for (int s = 0; s < TOPK; s++) { lv[tid * 8 + s] = tv[s]; li[tid * 8 + s] = ti[s]; }
    __syncthreads();
    for (int r = 0; r < TOPK; r++) {
        float bv = -2.f; int bi = 0x7fffffff; int bo = tid * 8;
        #pragma unroll
        for (int s = 0; s < TOPK; s++) {
            float v0 = lv[tid * 8 + s]; int i0 = li[tid * 8 + s];
            if (v0 > bv || (v0 == bv && i0 < bi)) { bv = v0; bi = i0; bo = tid * 8 + s; }
        }
        rv[tid] = bv; ri[tid] = bi; ro[tid] = bo;
        __syncthreads();
        for (int s = 128; s > 0; s >>= 1) {
            if (tid < s) {
                float v1 = rv[tid + s]; int i1 = ri[tid + s];
                if (v1 > rv[tid] || (v1 == rv[tid] && i1 < ri[tid])) {
                    rv[tid] = v1; ri[tid] = i1; ro[tid] = ro[tid + s];
                }
            }
            __syncthreads();
        }
        if (tid == 0) { outv[r] = rv[0]; outi[r] = ri[0]; lv[ro[0]] = -2.f; }
        __syncthreads();
    }
    if (tid == 0) {
        size_t rowid = (size_t)b * NDIM + i;
        float rm = fmaxf(rst, 1e-8f);
        float valid = fminf(rm * (float)(2 * NDIM), 1.f);
        float top1 = outv[0], top2 = outv[1];
        float pr = fminf(fmaxf(top1 / rm, 0.f), 1.f);
        float pm = fminf(fmaxf((top1 - top2) / rm, 0.f), 1.f);
        conf[rowid] = fminf(fmaxf((0.6f * pr + 0.4f * pm) * valid, 0.f), 1.f);
        bex[rowid * 2 + 0] = pxt / rm;
        bex[rowid * 2 + 1] = pyt / rm;
        #pragma unroll
        for (int k = 0; k < TOPK; k++) {
            tlogp[rowid * 8 + k] = logf(fmaxf(outv[k], 1e-38f));  // = Z+u+v (log-assign)
            float2 q = pb[outi[k]];
            tpos[(rowid * 8 + k) * 2 + 0] = q.x;
            tpos[(rowid * 8 + k) * 2 + 1] = q.y;
        }
    }
}

// -------- 6. geometric validation: 7x7 avg-pool (count_include_pad=False) --------
__global__ __launch_bounds__(256) void kgeo(const float* __restrict__ tpos,
                                            const float* __restrict__ posA,
                                            float* __restrict__ geo) {
    int b = blockIdx.x >> 3, k = blockIdx.x & 7;   // B*K = 16 blocks
    __shared__ float dx[4096], dy[4096];
    for (int hw = threadIdx.x; hw < 4096; hw += 256) {
        float2 pa = ((const float2*)posA)[(size_t)b * NDIM + hw];
        const float* tp = tpos + (((size_t)b * NDIM + hw) * 8 + k) * 2;
        dx[hw] = tp[0] - pa.x;
        dy[hw] = tp[1] - pa.y;
    }
    __syncthreads();
    for (int hw = threadIdx.x; hw < 4096; hw += 256) {
        int h = hw >> 6, ww = hw & 63;
        int h0 = max(h - 3, 0), h1 = min(h + 3, 63);
        int w0 = max(ww - 3, 0), w1 = min(ww + 3, 63);
        float sx = 0, sy = 0, sxx = 0, syy = 0;
        for (int hh = h0; hh <= h1; hh++)
            for (int wq = w0; wq <= w1; wq++) {
                float a = dx[hh * 64 + wq], c = dy[hh * 64 + wq];
                sx += a; sxx += a * a; sy += c; syy += c * c;
            }
        float cnt = (float)((h1 - h0 + 1) * (w1 - w0 + 1));
        float mx = sx / cnt, my = sy / cnt;
        float var = fmaxf(sxx / cnt - mx * mx, 0.f) + fmaxf(syy / cnt - my * my, 0.f);
        geo[((size_t)b * NDIM + hw) * 8 + k] = 1.f / (1.f + 100.f * var);
    }
}

// -------- 7. softmax over K, refine, confidence blend --------
__global__ void kblend(const float* __restrict__ conf, const float* __restrict__ bex,
                       const float* __restrict__ tlogp, const float* __restrict__ geo,
                       const float* __restrict__ tpos, const float* __restrict__ gwp,
                       float* __restrict__ out) {
    int t = blockIdx.x * 256 + threadIdx.x;
    if (t >= BDIM * NDIM) return;
    float gw = fminf(fmaxf(*gwp, 0.f), 2.f);
    float c[TOPK]; float m = -1e30f;
    #pragma unroll
    for (int k = 0; k < TOPK; k++) { c[k] = tlogp[t * 8 + k] + gw * geo[t * 8 + k]; m = fmaxf(m, c[k]); }
    float s = 0.f, rx = 0.f, ry = 0.f;
    #pragma unroll
    for (int k = 0; k < TOPK; k++) {
        float e = expf(c[k] - m);
        s += e;
        rx += e * tpos[(t * 8 + k) * 2 + 0];
        ry += e * tpos[(t * 8 + k) * 2 + 1];
    }
    float cf = conf[t];
    out[t * 2 + 0] = cf * (rx / s) + (1.f - cf) * bex[t * 2 + 0];
    out[t * 2 + 1] = cf * (ry / s) + (1.f - cf) * bex[t * 2 + 1];
}

extern "C" void kernel_launch(void* const* d_in, const int* in_sizes, int n_in,
                              void* d_out, int out_size, void* d_ws, size_t ws_size,
                              hipStream_t stream) {
    const float* featA = (const float*)d_in[0];
    const float* featB = (const float*)d_in[1];
    const float* posA  = (const float*)d_in[2];
    const float* posB  = (const float*)d_in[3];
    const float* dsp   = (const float*)d_in[4];
    const float* gwp   = (const float*)d_in[5];
    const float* tmpp  = (const float*)d_in[6];

    char* p = (char*)d_ws;
    size_t used = 0;
    auto alloc = [&](size_t bytes) -> void* {
        void* r = (void*)p;
        size_t a = (bytes + 255) & ~(size_t)255;
        p += a; used += a;
        return r;
    };
    __half* E             = (__half*)alloc((size_t)BDIM * NP * LDE * sizeof(__half));     // ~67.3 MB
    __hip_bfloat16* nA    = (__hip_bfloat16*)alloc((size_t)BDIM * NDIM * CDIM * 2);       // 2 MB
    __hip_bfloat16* nB    = (__hip_bfloat16*)alloc((size_t)BDIM * NDIM * CDIM * 2);       // 2 MB
    float* xu             = (float*)alloc((size_t)BDIM * NP * 4);
    float* w              = (float*)alloc((size_t)BDIM * NP * 4);
    float* cpart          = (float*)alloc((size_t)BDIM * NCH * LDE * 4);                  // ~1.1 MB
    float* conf           = (float*)alloc((size_t)BDIM * NDIM * 4);
    float* bex            = (float*)alloc((size_t)BDIM * NDIM * 8);
    float* tlogp          = (float*)alloc((size_t)BDIM * NDIM * TOPK * 4);
    float* tpos           = (float*)alloc((size_t)BDIM * NDIM * TOPK * 8);
    float* geo            = (float*)alloc((size_t)BDIM * NDIM * TOPK * 4);
    if (used > ws_size) return;   // need ~74 MB; fail visibly rather than corrupt

    knorm<<<BDIM * NDIM, 64, 0, stream>>>(featA, nA);
    knorm<<<BDIM * NDIM, 64, 0, stream>>>(featB, nB);
    kgemm<<<dim3(NDIM / 128, NDIM / 128, BDIM), 256, 0, stream>>>(nA, nB, E, tmpp);
    kdust<<<(2 * BDIM * NDIM + BDIM + 255) / 256, 256, 0, stream>>>(E, dsp, tmpp);
    kinitw<<<(BDIM * NP + 255) / 256, 256, 0, stream>>>(w);
    for (int it = 0; it < 15; ++it) {
        krow<<<dim3(NP, BDIM), 256, 0, stream>>>(E, w, xu);
        kcolp<<<dim3(9, NCH, BDIM), 256, 0, stream>>>(E, xu, cpart);
        kcolf<<<(BDIM * NP + 255) / 256, 256, 0, stream>>>(cpart, w);
    }
    kfinal<<<dim3(NDIM, BDIM), 256, 0, stream>>>(E, xu, w, posB, conf, bex, tlogp, tpos);
    kgeo<<<BDIM * TOPK, 256, 0, stream>>>(tpos, posA, geo);
    kblend<<<(BDIM * NDIM + 255) / 256, 256, 0, stream>>>(conf, bex, tlogp, geo, tpos, gwp, (float*)d_out);
}

// Round 3
// 696.862 us; speedup vs baseline: 1.5876x; 1.5876x over previous
//
#include <hip/hip_runtime.h>
#include <hip/hip_bf16.h>
#include <hip/hip_fp16.h>
#include <math.h>

#define BDIM 2
#define NDIM 4096
#define CDIM 128
#define NP   4097          // NDIM + 1 (dustbin)
#define LDE  4104          // leading dim of E, multiple of 8 for 16B-aligned rows
#define NCH  65            // row chunks for column pass (65*64 >= 4097)
#define CHROWS 64
#define TOPK 8

typedef __attribute__((ext_vector_type(8))) short short8;
typedef __attribute__((ext_vector_type(4))) float f32x4;

__device__ __forceinline__ bool kgt(float av, int ai, float bv, int bi) {
    return av > bv || (av == bv && ai < bi);
}

// merge two sorted-desc 8-lists (a in regs, b from caller) -> sorted-desc top-8 in a
__device__ __forceinline__ void merge8(float* av, int* ai, const float* bv, const int* bi) {
    float cv[TOPK]; int ci[TOPK];
    #pragma unroll
    for (int s = 0; s < TOPK; s++) {
        bool g = kgt(av[s], ai[s], bv[7 - s], bi[7 - s]);
        cv[s] = g ? av[s] : bv[7 - s];
        ci[s] = g ? ai[s] : bi[7 - s];
    }
    #pragma unroll
    for (int k = 4; k >= 1; k >>= 1)
        #pragma unroll
        for (int s = 0; s < TOPK; s++)
            if (!(s & k)) {
                int s2 = s | k;
                bool g = kgt(cv[s], ci[s], cv[s2], ci[s2]);
                float hv = g ? cv[s] : cv[s2]; int hi = g ? ci[s] : ci[s2];
                float lv = g ? cv[s2] : cv[s]; int li = g ? ci[s2] : ci[s];
                cv[s] = hv; ci[s] = hi; cv[s2] = lv; ci[s2] = li;
            }
    #pragma unroll
    for (int s = 0; s < TOPK; s++) { av[s] = cv[s]; ai[s] = ci[s]; }
}

// -------- 1. L2-normalize rows of A and B, write bf16 --------
__global__ __launch_bounds__(64) void knorm(const float* __restrict__ featA,
                                            const float* __restrict__ featB,
                                            __hip_bfloat16* __restrict__ outA,
                                            __hip_bfloat16* __restrict__ outB) {
    int row = blockIdx.x;               // 2*BDIM*NDIM rows
    const float* feat = featA;
    __hip_bfloat16* out = outA;
    if (row >= BDIM * NDIM) { feat = featB; out = outB; row -= BDIM * NDIM; }
    int t = threadIdx.x;                // 64 threads, 2 elems each
    const float2 x = ((const float2*)(feat + (size_t)row * CDIM))[t];
    float s = x.x * x.x + x.y * x.y;
    #pragma unroll
    for (int o = 32; o > 0; o >>= 1) s += __shfl_xor(s, o);
    float inv = 1.f / fmaxf(sqrtf(s), 1e-12f);
    __hip_bfloat16* o2 = out + (size_t)row * CDIM;
    o2[2 * t]     = __float2bfloat16(x.x * inv);
    o2[2 * t + 1] = __float2bfloat16(x.y * inv);
}

// -------- 2. scores GEMM (MFMA bf16) -> E = exp(clip(scores/temp)) fp16 --------
__global__ __launch_bounds__(256) void kgemm(const __hip_bfloat16* __restrict__ A16,
                                             const __hip_bfloat16* __restrict__ B16,
                                             __half* __restrict__ E,
                                             const float* __restrict__ tmpp) {
    int b = blockIdx.z;
    int i0 = blockIdx.y * 128, j0 = blockIdx.x * 128;
    int tid = threadIdx.x, lane = tid & 63, wv = tid >> 6;
    int wr = wv >> 1, wc = wv & 1;                 // 2x2 waves, 64x64 tile each
    const unsigned short* Ab = (const unsigned short*)A16 + (size_t)b * NDIM * CDIM;
    const unsigned short* Bb = (const unsigned short*)B16 + (size_t)b * NDIM * CDIM;
    int ar = i0 + wr * 64 + (lane & 15);
    int br = j0 + wc * 64 + (lane & 15);
    int koff = (lane >> 4) * 8;
    f32x4 acc[4][4] = {};
    for (int k0 = 0; k0 < CDIM; k0 += 32) {
        short8 a[4], bb[4];
        #pragma unroll
        for (int m = 0; m < 4; m++)
            a[m] = *(const short8*)(Ab + (size_t)(ar + m * 16) * CDIM + k0 + koff);
        #pragma unroll
        for (int n = 0; n < 4; n++)
            bb[n] = *(const short8*)(Bb + (size_t)(br + n * 16) * CDIM + k0 + koff);
        #pragma unroll
        for (int m = 0; m < 4; m++)
            #pragma unroll
            for (int n = 0; n < 4; n++)
                acc[m][n] = __builtin_amdgcn_mfma_f32_16x16x32_bf16(a[m], bb[n], acc[m][n], 0, 0, 0);
    }
    float temp = *tmpp;                 // reference divides by RAW temp here
    size_t ebase = (size_t)b * NP * LDE;
    int orow0 = (lane >> 4) * 4;
    int ocol = lane & 15;
    #pragma unroll
    for (int m = 0; m < 4; m++)
        #pragma unroll
        for (int n = 0; n < 4; n++) {
            int gj = j0 + wc * 64 + n * 16 + ocol;
            #pragma unroll
            for (int q = 0; q < 4; q++) {
                int gi = i0 + wr * 64 + m * 16 + orow0 + q;
                float s = acc[m][n][q] / temp;
                if (s != s) s = 0.f;                       // nan_to_num
                s = fminf(fmaxf(s, -50.f), 50.f);          // clip
                float e = fminf(expf(s), 60000.f);         // fp16-safe
                E[ebase + (size_t)gi * LDE + gj] = __float2half(e);
            }
        }
}

// -------- 3. dustbin row/col/corner + init w --------
__global__ void kdust(__half* __restrict__ E, const float* __restrict__ dsp,
                      const float* __restrict__ tmpp, float* __restrict__ w) {
    int t = blockIdx.x * 256 + threadIdx.x;
    float temp = fminf(fmaxf(*tmpp, 0.2f), 10.f);
    float ds = fminf(fmaxf((*dsp) / temp, -50.f), 50.f);
    __half e = __float2half(fminf(expf(ds), 60000.f));
    if (t < BDIM * NDIM) {
        int b = t / NDIM, j = t % NDIM;
        E[((size_t)b * NP + NDIM) * LDE + j] = e;          // dust row
    } else if (t < 2 * BDIM * NDIM) {
        int u2 = t - BDIM * NDIM;
        int b = u2 / NDIM, i = u2 % NDIM;
        E[((size_t)b * NP + i) * LDE + NDIM] = e;          // dust col
    } else if (t < 2 * BDIM * NDIM + BDIM) {
        int b = t - 2 * BDIM * NDIM;
        E[((size_t)b * NP + NDIM) * LDE + NDIM] = __float2half(1.f);  // corner exp(0)
    }
    if (t < BDIM * NP) w[t] = 1.f;     // v = 0 -> e^v = 1
}

// -------- 4a. row pass: one WAVE per row. r_i = sum_j E_ij*w_j; xu_i = mu_i/r_i --------
__global__ __launch_bounds__(256) void krow(const __half* __restrict__ E,
                                            const float* __restrict__ w,
                                            float* __restrict__ xu) {
    int rid = blockIdx.x * 4 + (threadIdx.x >> 6);   // global row over both batches
    if (rid >= BDIM * NP) return;
    int b = rid / NP, i = rid % NP;
    int lane = threadIdx.x & 63;
    const unsigned short* row = (const unsigned short*)E + ((size_t)b * NP + i) * LDE;
    const float* wb = w + (size_t)b * NP;
    float acc = 0.f;
    #pragma unroll
    for (int it = 0; it < 8; it++) {
        int j = (lane + 64 * it) * 8;
        short8 raw = *(const short8*)(row + j);
        float4 w0 = ((const float4*)(wb + j))[0];
        float4 w1 = ((const float4*)(wb + j))[1];
        acc += __half2float(__ushort_as_half((unsigned short)raw[0])) * w0.x;
        acc += __half2float(__ushort_as_half((unsigned short)raw[1])) * w0.y;
        acc += __half2float(__ushort_as_half((unsigned short)raw[2])) * w0.z;
        acc += __half2float(__ushort_as_half((unsigned short)raw[3])) * w0.w;
        acc += __half2float(__ushort_as_half((unsigned short)raw[4])) * w1.x;
        acc += __half2float(__ushort_as_half((unsigned short)raw[5])) * w1.y;
        acc += __half2float(__ushort_as_half((unsigned short)raw[6])) * w1.z;
        acc += __half2float(__ushort_as_half((unsigned short)raw[7])) * w1.w;
    }
    if (lane == 0) acc += __half2float(__ushort_as_half(row[NDIM])) * wb[NDIM];
    #pragma unroll
    for (int o = 32; o > 0; o >>= 1) acc += __shfl_xor(acc, o);
    if (lane == 0) {
        float mu = (i == NDIM) ? 0.5f : (1.f / 8192.f);
        xu[rid] = mu / fmaxf(acc, 1e-35f);
    }
}

// -------- 4b. column pass partials --------
__global__ __launch_bounds__(256) void kcolp(const __half* __restrict__ E,
                                             const float* __restrict__ xu,
                                             float* __restrict__ cpart) {
    int b = blockIdx.z, ch = blockIdx.y, pan = blockIdx.x;
    int j = pan * 512 + threadIdx.x * 2;
    if (j >= NP) return;
    int r0 = ch * CHROWS, r1 = min(r0 + CHROWS, NP);
    const __half* base = E + (size_t)b * NP * LDE + j;
    const float* xb = xu + (size_t)b * NP;
    float a0 = 0.f, a1 = 0.f, b0 = 0.f, b1 = 0.f;
    int i = r0;
    for (; i + 1 < r1; i += 2) {
        float x0 = xb[i], x1 = xb[i + 1];
        float2 e0 = __half22float2(*(const __half2*)(base + (size_t)i * LDE));
        float2 e1 = __half22float2(*(const __half2*)(base + (size_t)(i + 1) * LDE));
        a0 += e0.x * x0; a1 += e0.y * x0;
        b0 += e1.x * x1; b1 += e1.y * x1;
    }
    if (i < r1) {
        float x0 = xb[i];
        float2 e0 = __half22float2(*(const __half2*)(base + (size_t)i * LDE));
        a0 += e0.x * x0; a1 += e0.y * x0;
    }
    float* cp = cpart + ((size_t)b * NCH + ch) * LDE;
    cp[j] = a0 + b0;
    if (j + 1 < NP) cp[j + 1] = a1 + b1;
}

// -------- 4c. finish: w_j = nu_j / sum_ch cpart --------
__global__ void kcolf(const float* __restrict__ cpart, float* __restrict__ w) {
    int t = blockIdx.x * 256 + threadIdx.x;
    if (t >= BDIM * NP) return;
    int b = t / NP, j = t % NP;
    float s = 0.f;
    for (int ch = 0; ch < NCH; ch++) s += cpart[((size_t)b * NCH + ch) * LDE + j];
    float nu = (j == NDIM) ? 0.5f : (1.f / 8192.f);
    w[t] = nu / fmaxf(s, 1e-35f);
}

// -------- 5. final row pass: row mass, expected pos, top-8 via padded-LDS tree merge --------
__global__ __launch_bounds__(256) void kfinal(const __half* __restrict__ E,
                                              const float* __restrict__ xu,
                                              const float* __restrict__ w,
                                              const float* __restrict__ posB,
                                              float* __restrict__ conf,
                                              float* __restrict__ bex,
                                              float* __restrict__ tlogp,
                                              float* __restrict__ tpos) {
    int b = blockIdx.y, i = blockIdx.x;   // i < NDIM
    int tid = threadIdx.x, lane = tid & 63, wv = tid >> 6;
    const unsigned short* row = (const unsigned short*)E + ((size_t)b * NP + i) * LDE;
    const float* wb = w + (size_t)b * NP;
    const float2* pb = (const float2*)posB + (size_t)b * NDIM;
    float eu = xu[(size_t)b * NP + i];
    float rs = 0.f, px = 0.f, py = 0.f;
    float tv[TOPK]; int ti[TOPK];
    #pragma unroll
    for (int s = 0; s < TOPK; s++) { tv[s] = -1.f; ti[s] = 0x7fffffff; }
    // scan: 512 chunks of 8; thread handles chunks tid and tid+256 (coalesced 16B)
    #pragma unroll
    for (int c = 0; c < 2; c++) {
        int j = (tid + c * 256) * 8;
        short8 raw = *(const short8*)(row + j);
        float4 w0 = ((const float4*)(wb + j))[0];
        float4 w1 = ((const float4*)(wb + j))[1];
        float wj[8] = {w0.x, w0.y, w0.z, w0.w, w1.x, w1.y, w1.z, w1.w};
        #pragma unroll
        for (int e = 0; e < 8; e++) {
            int jj = j + e;
            float p = __half2float(__ushort_as_half((unsigned short)raw[e])) * wj[e];
            float2 q = pb[jj];
            rs += p; px += p * q.x; py += p * q.y;
            if (kgt(p, jj, tv[7], ti[7])) {      // only if it belongs in top-8
                float pv = p; int pj = jj;
                #pragma unroll
                for (int s = 0; s < TOPK; s++) {
                    bool g = kgt(pv, pj, tv[s], ti[s]);
                    float nv = g ? pv : tv[s]; int ni = g ? pj : ti[s];
                    float ov = g ? tv[s] : pv; int oi = g ? ti[s] : pj;
                    tv[s] = nv; ti[s] = ni; pv = ov; pj = oi;
                }
            }
        }
    }
    // ---- wave-level sum reduce for rs/px/py ----
    #pragma unroll
    for (int o = 32; o > 0; o >>= 1) {
        rs += __shfl_xor(rs, o); px += __shfl_xor(px, o); py += __shfl_xor(py, o);
    }
    __shared__ float red[3][4];
    if (lane == 0) { red[0][wv] = rs; red[1][wv] = px; red[2][wv] = py; }
    // ---- padded-LDS tree merge of 256 sorted-8 lists (stride 9: conflict-free) ----
    __shared__ float lv[256 * 9];
    __shared__ int   li[256 * 9];
    #pragma unroll
    for (int s = 0; s < TOPK; s++) { lv[tid * 9 + s] = tv[s]; li[tid * 9 + s] = ti[s]; }
    __syncthreads();
    for (int step = 1; step < 256; step <<= 1) {
        if ((tid & (2 * step - 1)) == 0) {
            float bv[TOPK]; int bi[TOPK];
            int o = (tid + step) * 9;
            #pragma unroll
            for (int s = 0; s < TOPK; s++) { bv[s] = lv[o + s]; bi[s] = li[o + s]; }
            merge8(tv, ti, bv, bi);
            if (step < 128) {   // last level: result stays in tid 0's registers
                #pragma unroll
                for (int s = 0; s < TOPK; s++) { lv[tid * 9 + s] = tv[s]; li[tid * 9 + s] = ti[s]; }
            }
        }
        __syncthreads();
    }
    if (tid == 0) {
        float rst = red[0][0] + red[0][1] + red[0][2] + red[0][3];
        float pxt = red[1][0] + red[1][1] + red[1][2] + red[1][3];
        float pyt = red[2][0] + red[2][1] + red[2][2] + red[2][3];
        size_t rowid = (size_t)b * NDIM + i;
        float rm = fmaxf(rst * eu, 1e-8f);             // true row mass
        float valid = fminf(rm * (float)(2 * NDIM), 1.f);
        float top1 = tv[0] * eu, top2 = tv[1] * eu;
        float pr = fminf(fmaxf(top1 / rm, 0.f), 1.f);
        float pm = fminf(fmaxf((top1 - top2) / rm, 0.f), 1.f);
        conf[rowid] = fminf(fmaxf((0.6f * pr + 0.4f * pm) * valid, 0.f), 1.f);
        bex[rowid * 2 + 0] = pxt * eu / rm;
        bex[rowid * 2 + 1] = pyt * eu / rm;
        #pragma unroll
        for (int k = 0; k < TOPK; k++) {
            tlogp[rowid * 8 + k] = logf(fmaxf(tv[k] * eu, 1e-38f));
            float2 q = pb[ti[k]];
            tpos[(rowid * 8 + k) * 2 + 0] = q.x;
            tpos[(rowid * 8 + k) * 2 + 1] = q.y;
        }
    }
}

// -------- 6. geometric validation: 7x7 avg-pool (count_include_pad=False) --------
__global__ __launch_bounds__(256) void kgeo(const float* __restrict__ tpos,
                                            const float* __restrict__ posA,
                                            float* __restrict__ geo) {
    int b = blockIdx.x >> 3, k = blockIdx.x & 7;   // B*K = 16 blocks
    __shared__ float dx[4096], dy[4096];
    for (int hw = threadIdx.x; hw < 4096; hw += 256) {
        float2 pa = ((const float2*)posA)[(size_t)b * NDIM + hw];
        const float* tp = tpos + (((size_t)b * NDIM + hw) * 8 + k) * 2;
        dx[hw] = tp[0] - pa.x;
        dy[hw] = tp[1] - pa.y;
    }
    __syncthreads();
    for (int hw = threadIdx.x; hw < 4096; hw += 256) {
        int h = hw >> 6, ww = hw & 63;
        int h0 = max(h - 3, 0), h1 = min(h + 3, 63);
        int w0 = max(ww - 3, 0), w1 = min(ww + 3, 63);
        float sx = 0, sy = 0, sxx = 0, syy = 0;
        for (int hh = h0; hh <= h1; hh++)
            for (int wq = w0; wq <= w1; wq++) {
                float a = dx[hh * 64 + wq], c = dy[hh * 64 + wq];
                sx += a; sxx += a * a; sy += c; syy += c * c;
            }
        float cnt = (float)((h1 - h0 + 1) * (w1 - w0 + 1));
        float mx = sx / cnt, my = sy / cnt;
        float var = fmaxf(sxx / cnt - mx * mx, 0.f) + fmaxf(syy / cnt - my * my, 0.f);
        geo[((size_t)b * NDIM + hw) * 8 + k] = 1.f / (1.f + 100.f * var);
    }
}

// -------- 7. softmax over K, refine, confidence blend --------
__global__ void kblend(const float* __restrict__ conf, const float* __restrict__ bex,
                       const float* __restrict__ tlogp, const float* __restrict__ geo,
                       const float* __restrict__ tpos, const float* __restrict__ gwp,
                       float* __restrict__ out) {
    int t = blockIdx.x * 256 + threadIdx.x;
    if (t >= BDIM * NDIM) return;
    float gw = fminf(fmaxf(*gwp, 0.f), 2.f);
    float c[TOPK]; float m = -1e30f;
    #pragma unroll
    for (int k = 0; k < TOPK; k++) { c[k] = tlogp[t * 8 + k] + gw * geo[t * 8 + k]; m = fmaxf(m, c[k]); }
    float s = 0.f, rx = 0.f, ry = 0.f;
    #pragma unroll
    for (int k = 0; k < TOPK; k++) {
        float e = expf(c[k] - m);
        s += e;
        rx += e * tpos[(t * 8 + k) * 2 + 0];
        ry += e * tpos[(t * 8 + k) * 2 + 1];
    }
    float cf = conf[t];
    out[t * 2 + 0] = cf * (rx / s) + (1.f - cf) * bex[t * 2 + 0];
    out[t * 2 + 1] = cf * (ry / s) + (1.f - cf) * bex[t * 2 + 1];
}

extern "C" void kernel_launch(void* const* d_in, const int* in_sizes, int n_in,
                              void* d_out, int out_size, void* d_ws, size_t ws_size,
                              hipStream_t stream) {
    const float* featA = (const float*)d_in[0];
    const float* featB = (const float*)d_in[1];
    const float* posA  = (const float*)d_in[2];
    const float* posB  = (const float*)d_in[3];
    const float* dsp   = (const float*)d_in[4];
    const float* gwp   = (const float*)d_in[5];
    const float* tmpp  = (const float*)d_in[6];

    char* p = (char*)d_ws;
    size_t used = 0;
    auto alloc = [&](size_t bytes) -> void* {
        void* r = (void*)p;
        size_t a = (bytes + 255) & ~(size_t)255;
        p += a; used += a;
        return r;
    };
    __half* E             = (__half*)alloc((size_t)BDIM * NP * LDE * sizeof(__half));     // ~67.3 MB
    __hip_bfloat16* nA    = (__hip_bfloat16*)alloc((size_t)BDIM * NDIM * CDIM * 2);       // 2 MB
    __hip_bfloat16* nB    = (__hip_bfloat16*)alloc((size_t)BDIM * NDIM * CDIM * 2);       // 2 MB
    float* xu             = (float*)alloc((size_t)BDIM * NP * 4);
    float* w              = (float*)alloc((size_t)BDIM * NP * 4);
    float* cpart          = (float*)alloc((size_t)BDIM * NCH * LDE * 4);                  // ~2.1 MB
    float* conf           = (float*)alloc((size_t)BDIM * NDIM * 4);
    float* bex            = (float*)alloc((size_t)BDIM * NDIM * 8);
    float* tlogp          = (float*)alloc((size_t)BDIM * NDIM * TOPK * 4);
    float* tpos           = (float*)alloc((size_t)BDIM * NDIM * TOPK * 8);
    float* geo            = (float*)alloc((size_t)BDIM * NDIM * TOPK * 4);
    if (used > ws_size) return;   // need ~75 MB; fail visibly rather than corrupt

    knorm<<<2 * BDIM * NDIM, 64, 0, stream>>>(featA, featB, nA, nB);
    kgemm<<<dim3(NDIM / 128, NDIM / 128, BDIM), 256, 0, stream>>>(nA, nB, E, tmpp);
    kdust<<<(2 * BDIM * NDIM + BDIM + 255) / 256, 256, 0, stream>>>(E, dsp, tmpp, w);
    for (int it = 0; it < 15; ++it) {
        krow<<<(BDIM * NP + 3) / 4, 256, 0, stream>>>(E, w, xu);
        kcolp<<<dim3(9, NCH, BDIM), 256, 0, stream>>>(E, xu, cpart);
        kcolf<<<(BDIM * NP + 255) / 256, 256, 0, stream>>>(cpart, w);
    }
    kfinal<<<dim3(NDIM, BDIM), 256, 0, stream>>>(E, xu, w, posB, conf, bex, tlogp, tpos);
    kgeo<<<BDIM * TOPK, 256, 0, stream>>>(tpos, posA, geo);
    kblend<<<(BDIM * NDIM + 255) / 256, 256, 0, stream>>>(conf, bex, tlogp, geo, tpos, gwp, (float*)d_out);
}

// Round 4
// 687.557 us; speedup vs baseline: 1.6091x; 1.0135x over previous
//
#include <hip/hip_runtime.h>
#include <hip/hip_bf16.h>
#include <hip/hip_fp16.h>
#include <math.h>

#define BDIM 2
#define NDIM 4096
#define CDIM 128
#define NP   4097          // NDIM + 1 (dustbin)
#define LDE  4104          // leading dim of E fp16 (8-aligned rows)
#define LDE8 4112          // leading dim of E fp8 (16-aligned rows for uint4 loads)
#define NCH  65            // row chunks for column pass (65*64 >= 4097)
#define CHROWS 64
#define TOPK 8

typedef __attribute__((ext_vector_type(8))) short short8;
typedef __attribute__((ext_vector_type(4))) float f32x4;
typedef __attribute__((ext_vector_type(2))) float f32x2;

#if defined(__has_builtin)
#if __has_builtin(__builtin_amdgcn_cvt_pk_f32_fp8) && __has_builtin(__builtin_amdgcn_cvt_pk_fp8_f32)
#define HWFP8 1
#endif
#endif

// ---- fp8 e4m3 helpers (positive values only; hw path + manual fallback) ----
__device__ __forceinline__ unsigned char fp8_encode_pos(float x) {
    // round-to-nearest-even e4m3, x in (0, 448]
    unsigned u = __float_as_uint(x);
    int e = (int)((u >> 23) & 0xff) - 127;
    if (e < -6) {
        unsigned m = (unsigned)(x * 512.f + 0.5f);
        return (unsigned char)(m > 7 ? 7 : m);
    }
    unsigned mant = u & 0x7fffff;
    unsigned keep = mant >> 20;
    unsigned rest = mant & 0xfffff;
    unsigned rnd = (rest > 0x80000u) || (rest == 0x80000u && (keep & 1));
    keep += rnd;
    if (keep == 8) { keep = 0; e += 1; }
    if (e > 8) { keep = 7; e = 8; }
    return (unsigned char)(((e + 7) << 3) | keep);
}
__device__ __forceinline__ float fp8_decode_pos(unsigned q) {
    unsigned e = (q >> 3) & 0xf, m = q & 7;
    unsigned fn = ((e + 120) << 23) | (m << 20);
    float vs = (float)m * (1.f / 512.f);
    return e ? __uint_as_float(fn) : vs;
}
__device__ __forceinline__ unsigned char enc1(float x) {
#ifdef HWFP8
    int pk = __builtin_amdgcn_cvt_pk_fp8_f32(x, x, 0, false);
    return (unsigned char)(pk & 0xff);
#else
    return fp8_encode_pos(x);
#endif
}
__device__ __forceinline__ void dec4(unsigned v, float* o) {
#ifdef HWFP8
    f32x2 lo = __builtin_amdgcn_cvt_pk_f32_fp8((int)v, false);
    f32x2 hi = __builtin_amdgcn_cvt_pk_f32_fp8((int)v, true);
    o[0] = lo[0]; o[1] = lo[1]; o[2] = hi[0]; o[3] = hi[1];
#else
    o[0] = fp8_decode_pos(v & 0xff); o[1] = fp8_decode_pos((v >> 8) & 0xff);
    o[2] = fp8_decode_pos((v >> 16) & 0xff); o[3] = fp8_decode_pos((v >> 24) & 0xff);
#endif
}

// ---- u64 key sorting primitives (key = value-bits desc, ~index) ----
__device__ __forceinline__ void ce(unsigned long long& x, unsigned long long& y) {
    bool g = x > y;
    unsigned long long hi = g ? x : y, lo = g ? y : x;
    x = hi; y = lo;
}
__device__ __forceinline__ void sort8(unsigned long long* k) {   // descending
    ce(k[0],k[1]); ce(k[2],k[3]); ce(k[4],k[5]); ce(k[6],k[7]);
    ce(k[0],k[2]); ce(k[1],k[3]); ce(k[4],k[6]); ce(k[5],k[7]);
    ce(k[1],k[2]); ce(k[5],k[6]);
    ce(k[0],k[4]); ce(k[1],k[5]); ce(k[2],k[6]); ce(k[3],k[7]);
    ce(k[2],k[4]); ce(k[3],k[5]);
    ce(k[1],k[2]); ce(k[3],k[4]); ce(k[5],k[6]);
}
__device__ __forceinline__ void merge8u(unsigned long long* a, const unsigned long long* b) {
    unsigned long long c[TOPK];
    #pragma unroll
    for (int s = 0; s < TOPK; s++) c[s] = a[s] > b[7 - s] ? a[s] : b[7 - s];
    #pragma unroll
    for (int k = 4; k >= 1; k >>= 1)
        #pragma unroll
        for (int s = 0; s < TOPK; s++)
            if (!(s & k)) { int s2 = s | k; ce(c[s], c[s2]); }
    #pragma unroll
    for (int s = 0; s < TOPK; s++) a[s] = c[s];
}

// -------- 1. L2-normalize rows of A and B, write bf16 --------
__global__ __launch_bounds__(64) void knorm(const float* __restrict__ featA,
                                            const float* __restrict__ featB,
                                            __hip_bfloat16* __restrict__ outA,
                                            __hip_bfloat16* __restrict__ outB) {
    int row = blockIdx.x;               // 2*BDIM*NDIM rows
    const float* feat = featA;
    __hip_bfloat16* out = outA;
    if (row >= BDIM * NDIM) { feat = featB; out = outB; row -= BDIM * NDIM; }
    int t = threadIdx.x;
    const float2 x = ((const float2*)(feat + (size_t)row * CDIM))[t];
    float s = x.x * x.x + x.y * x.y;
    #pragma unroll
    for (int o = 32; o > 0; o >>= 1) s += __shfl_xor(s, o);
    float inv = 1.f / fmaxf(sqrtf(s), 1e-12f);
    __hip_bfloat16* o2 = out + (size_t)row * CDIM;
    o2[2 * t]     = __float2bfloat16(x.x * inv);
    o2[2 * t + 1] = __float2bfloat16(x.y * inv);
}

// -------- 2. scores GEMM (MFMA bf16) -> E16 fp16 + E8 fp8 --------
__global__ __launch_bounds__(256) void kgemm(const __hip_bfloat16* __restrict__ A16,
                                             const __hip_bfloat16* __restrict__ B16,
                                             __half* __restrict__ E,
                                             unsigned char* __restrict__ E8,
                                             const float* __restrict__ tmpp) {
    int b = blockIdx.z;
    int i0 = blockIdx.y * 128, j0 = blockIdx.x * 128;
    int tid = threadIdx.x, lane = tid & 63, wv = tid >> 6;
    int wr = wv >> 1, wc = wv & 1;
    const unsigned short* Ab = (const unsigned short*)A16 + (size_t)b * NDIM * CDIM;
    const unsigned short* Bb = (const unsigned short*)B16 + (size_t)b * NDIM * CDIM;
    int ar = i0 + wr * 64 + (lane & 15);
    int br = j0 + wc * 64 + (lane & 15);
    int koff = (lane >> 4) * 8;
    f32x4 acc[4][4] = {};
    for (int k0 = 0; k0 < CDIM; k0 += 32) {
        short8 a[4], bb[4];
        #pragma unroll
        for (int m = 0; m < 4; m++)
            a[m] = *(const short8*)(Ab + (size_t)(ar + m * 16) * CDIM + k0 + koff);
        #pragma unroll
        for (int n = 0; n < 4; n++)
            bb[n] = *(const short8*)(Bb + (size_t)(br + n * 16) * CDIM + k0 + koff);
        #pragma unroll
        for (int m = 0; m < 4; m++)
            #pragma unroll
            for (int n = 0; n < 4; n++)
                acc[m][n] = __builtin_amdgcn_mfma_f32_16x16x32_bf16(a[m], bb[n], acc[m][n], 0, 0, 0);
    }
    float temp = *tmpp;
    size_t ebase = (size_t)b * NP * LDE;
    size_t e8base = (size_t)b * NP * LDE8;
    int orow0 = (lane >> 4) * 4;
    int ocol = lane & 15;
    #pragma unroll
    for (int m = 0; m < 4; m++)
        #pragma unroll
        for (int n = 0; n < 4; n++) {
            int gj = j0 + wc * 64 + n * 16 + ocol;
            #pragma unroll
            for (int q = 0; q < 4; q++) {
                int gi = i0 + wr * 64 + m * 16 + orow0 + q;
                float s = acc[m][n][q] / temp;
                if (s != s) s = 0.f;
                s = fminf(fmaxf(s, -50.f), 50.f);
                float e = fminf(expf(s), 60000.f);
                E[ebase + (size_t)gi * LDE + gj] = __float2half(e);
                E8[e8base + (size_t)gi * LDE8 + gj] = enc1(fminf(e, 440.f));
            }
        }
}

// -------- 3. dustbin row/col/corner + init w --------
__global__ void kdust(__half* __restrict__ E, unsigned char* __restrict__ E8,
                      const float* __restrict__ dsp,
                      const float* __restrict__ tmpp, float* __restrict__ w) {
    int t = blockIdx.x * 256 + threadIdx.x;
    float temp = fminf(fmaxf(*tmpp, 0.2f), 10.f);
    float ds = fminf(fmaxf((*dsp) / temp, -50.f), 50.f);
    float ev = fminf(expf(ds), 60000.f);
    __half e = __float2half(ev);
    unsigned char e8 = enc1(fminf(ev, 440.f));
    if (t < BDIM * NDIM) {
        int b = t / NDIM, j = t % NDIM;
        E[((size_t)b * NP + NDIM) * LDE + j] = e;            // dust row
        E8[((size_t)b * NP + NDIM) * LDE8 + j] = e8;
    } else if (t < 2 * BDIM * NDIM) {
        int u2 = t - BDIM * NDIM;
        int b = u2 / NDIM, i = u2 % NDIM;
        E[((size_t)b * NP + i) * LDE + NDIM] = e;            // dust col
        E8[((size_t)b * NP + i) * LDE8 + NDIM] = e8;
    } else if (t < 2 * BDIM * NDIM + BDIM) {
        int b = t - 2 * BDIM * NDIM;
        E[((size_t)b * NP + NDIM) * LDE + NDIM] = __float2half(1.f);   // corner
        E8[((size_t)b * NP + NDIM) * LDE8 + NDIM] = enc1(1.f);
    }
    if (t < BDIM * NP) w[t] = 1.f;
}

// -------- 4a. row pass (fp8): one WAVE per row --------
__global__ __launch_bounds__(256) void krow(const unsigned char* __restrict__ E8,
                                            const float* __restrict__ w,
                                            float* __restrict__ xu) {
    int rid = blockIdx.x * 4 + (threadIdx.x >> 6);
    if (rid >= BDIM * NP) return;
    int b = rid / NP, i = rid - b * NP;
    int lane = threadIdx.x & 63;
    const unsigned char* rowb = E8 + ((size_t)b * NP + i) * LDE8;
    const uint4* row = (const uint4*)rowb;
    const float* wb = w + (size_t)b * NP;
    float acc = 0.f;
    #pragma unroll
    for (int it = 0; it < 4; it++) {
        int c = lane + 64 * it;             // 16-byte chunk -> cols c*16..c*16+15
        uint4 v = row[c];
        const float4* wp = (const float4*)(wb + c * 16);
        float4 wa = wp[0], wbv = wp[1], wcv = wp[2], wdv = wp[3];
        float d[16];
        dec4(v.x, d); dec4(v.y, d + 4); dec4(v.z, d + 8); dec4(v.w, d + 12);
        acc += d[0] * wa.x + d[1] * wa.y + d[2] * wa.z + d[3] * wa.w;
        acc += d[4] * wbv.x + d[5] * wbv.y + d[6] * wbv.z + d[7] * wbv.w;
        acc += d[8] * wcv.x + d[9] * wcv.y + d[10] * wcv.z + d[11] * wcv.w;
        acc += d[12] * wdv.x + d[13] * wdv.y + d[14] * wdv.z + d[15] * wdv.w;
    }
    if (lane == 0) {
        float dd[4];
        dec4((unsigned)rowb[NDIM], dd);
        acc += dd[0] * wb[NDIM];
    }
    #pragma unroll
    for (int o = 32; o > 0; o >>= 1) acc += __shfl_xor(acc, o);
    if (lane == 0) {
        float mu = (i == NDIM) ? 0.5f : (1.f / 8192.f);
        xu[rid] = mu / fmaxf(acc, 1e-35f);
    }
}

// -------- 4b. column pass partials (fp8) --------
__global__ __launch_bounds__(256) void kcolp(const unsigned char* __restrict__ E8,
                                             const float* __restrict__ xu,
                                             float* __restrict__ cpart) {
    int b = blockIdx.z, ch = blockIdx.y, pan = blockIdx.x;
    int j = pan * 1024 + threadIdx.x * 4;
    if (j >= NP) return;
    int r0 = ch * CHROWS, r1 = min(r0 + CHROWS, NP);
    const unsigned char* base = E8 + (size_t)b * NP * LDE8 + j;
    const float* xb = xu + (size_t)b * NP;
    float a0 = 0, a1 = 0, a2 = 0, a3 = 0, c0 = 0, c1 = 0, c2 = 0, c3 = 0;
    int i = r0;
    for (; i + 1 < r1; i += 2) {
        unsigned v0 = *(const unsigned*)(base + (size_t)i * LDE8);
        unsigned v1 = *(const unsigned*)(base + (size_t)(i + 1) * LDE8);
        float x0 = xb[i], x1 = xb[i + 1];
        float d0[4], d1[4];
        dec4(v0, d0); dec4(v1, d1);
        a0 += d0[0] * x0; a1 += d0[1] * x0; a2 += d0[2] * x0; a3 += d0[3] * x0;
        c0 += d1[0] * x1; c1 += d1[1] * x1; c2 += d1[2] * x1; c3 += d1[3] * x1;
    }
    if (i < r1) {
        unsigned v0 = *(const unsigned*)(base + (size_t)i * LDE8);
        float x0 = xb[i];
        float d0[4];
        dec4(v0, d0);
        a0 += d0[0] * x0; a1 += d0[1] * x0; a2 += d0[2] * x0; a3 += d0[3] * x0;
    }
    float* cp = cpart + ((size_t)b * NCH + ch) * LDE;
    cp[j] = a0 + c0;
    if (j + 1 < NP) cp[j + 1] = a1 + c1;
    if (j + 2 < NP) cp[j + 2] = a2 + c2;
    if (j + 3 < NP) cp[j + 3] = a3 + c3;
}

// -------- 4c. finish: w_j = nu_j / sum_ch cpart --------
__global__ void kcolf(const float* __restrict__ cpart, float* __restrict__ w) {
    int t = blockIdx.x * 256 + threadIdx.x;
    if (t >= BDIM * NP) return;
    int b = t / NP, j = t % NP;
    float s = 0.f;
    for (int ch = 0; ch < NCH; ch++) s += cpart[((size_t)b * NCH + ch) * LDE + j];
    float nu = (j == NDIM) ? 0.5f : (1.f / 8192.f);
    w[t] = nu / fmaxf(s, 1e-35f);
}

// -------- 5. final row pass: 512 thr, sort8 + u64-key LDS tree merge --------
__global__ __launch_bounds__(512) void kfinal(const __half* __restrict__ E,
                                              const float* __restrict__ xu,
                                              const float* __restrict__ w,
                                              const float* __restrict__ posB,
                                              float* __restrict__ conf,
                                              float* __restrict__ bex,
                                              float* __restrict__ tlogp,
                                              float* __restrict__ tpos) {
    int b = blockIdx.y, i = blockIdx.x;   // i < NDIM
    int tid = threadIdx.x, lane = tid & 63, wv = tid >> 6;   // 8 waves
    const unsigned short* row = (const unsigned short*)E + ((size_t)b * NP + i) * LDE;
    const float* wb = w + (size_t)b * NP;
    const float2* pb = (const float2*)posB + (size_t)b * NDIM;
    float eu = xu[(size_t)b * NP + i];
    int j = tid * 8;
    short8 raw = *(const short8*)(row + j);
    float4 w0 = ((const float4*)(wb + j))[0];
    float4 w1 = ((const float4*)(wb + j))[1];
    float wj[8] = {w0.x, w0.y, w0.z, w0.w, w1.x, w1.y, w1.z, w1.w};
    float rs = 0.f, px = 0.f, py = 0.f;
    unsigned long long kk[TOPK];
    #pragma unroll
    for (int e = 0; e < 8; e++) {
        int jj = j + e;
        float p = __half2float(__ushort_as_half((unsigned short)raw[e])) * wj[e];
        float2 q = pb[jj];
        rs += p; px += p * q.x; py += p * q.y;
        kk[e] = ((unsigned long long)__float_as_uint(p) << 32) | (unsigned)(~jj);
    }
    sort8(kk);
    // wave reduce sums
    #pragma unroll
    for (int o = 32; o > 0; o >>= 1) {
        rs += __shfl_xor(rs, o); px += __shfl_xor(px, o); py += __shfl_xor(py, o);
    }
    __shared__ float redv[3][8];
    __shared__ unsigned long long lk[512 * 9];
    __shared__ unsigned long long fin[TOPK];
    if (lane == 0) { redv[0][wv] = rs; redv[1][wv] = px; redv[2][wv] = py; }
    #pragma unroll
    for (int s = 0; s < TOPK; s++) lk[tid * 9 + s] = kk[s];
    __syncthreads();
    for (int step = 1; step < 512; step <<= 1) {
        if ((tid & (2 * step - 1)) == 0) {
            unsigned long long pk[TOPK];
            int o = (tid + step) * 9;
            #pragma unroll
            for (int s = 0; s < TOPK; s++) pk[s] = lk[o + s];
            merge8u(kk, pk);
            if (step < 256) {
                #pragma unroll
                for (int s = 0; s < TOPK; s++) lk[tid * 9 + s] = kk[s];
            }
        }
        __syncthreads();
    }
    if (tid == 0) {
        #pragma unroll
        for (int s = 0; s < TOPK; s++) fin[s] = kk[s];
    }
    __syncthreads();
    size_t rowid = (size_t)b * NDIM + i;
    if (tid < TOPK) {
        unsigned long long key = fin[tid];
        float val = __uint_as_float((unsigned)(key >> 32)) * eu;
        int jj = (int)(~(unsigned)key);
        tlogp[rowid * 8 + tid] = logf(fmaxf(val, 1e-38f));
        float2 q = pb[jj];
        tpos[(rowid * 8 + tid) * 2 + 0] = q.x;
        tpos[(rowid * 8 + tid) * 2 + 1] = q.y;
    }
    if (tid == 0) {
        float rst = 0, pxt = 0, pyt = 0;
        #pragma unroll
        for (int q = 0; q < 8; q++) { rst += redv[0][q]; pxt += redv[1][q]; pyt += redv[2][q]; }
        float rm = fmaxf(rst * eu, 1e-8f);
        float valid = fminf(rm * (float)(2 * NDIM), 1.f);
        float top1 = __uint_as_float((unsigned)(fin[0] >> 32)) * eu;
        float top2 = __uint_as_float((unsigned)(fin[1] >> 32)) * eu;
        float pr = fminf(fmaxf(top1 / rm, 0.f), 1.f);
        float pm = fminf(fmaxf((top1 - top2) / rm, 0.f), 1.f);
        conf[rowid] = fminf(fmaxf((0.6f * pr + 0.4f * pm) * valid, 0.f), 1.f);
        bex[rowid * 2 + 0] = pxt * eu / rm;
        bex[rowid * 2 + 1] = pyt * eu / rm;
    }
}

// -------- 6. geometric validation: 7x7 avg-pool (count_include_pad=False) --------
__global__ __launch_bounds__(256) void kgeo(const float* __restrict__ tpos,
                                            const float* __restrict__ posA,
                                            float* __restrict__ geo) {
    int b = blockIdx.x >> 3, k = blockIdx.x & 7;
    __shared__ float dx[4096], dy[4096];
    for (int hw = threadIdx.x; hw < 4096; hw += 256) {
        float2 pa = ((const float2*)posA)[(size_t)b * NDIM + hw];
        const float* tp = tpos + (((size_t)b * NDIM + hw) * 8 + k) * 2;
        dx[hw] = tp[0] - pa.x;
        dy[hw] = tp[1] - pa.y;
    }
    __syncthreads();
    for (int hw = threadIdx.x; hw < 4096; hw += 256) {
        int h = hw >> 6, ww = hw & 63;
        int h0 = max(h - 3, 0), h1 = min(h + 3, 63);
        int w0 = max(ww - 3, 0), w1 = min(ww + 3, 63);
        float sx = 0, sy = 0, sxx = 0, syy = 0;
        for (int hh = h0; hh <= h1; hh++)
            for (int wq = w0; wq <= w1; wq++) {
                float a = dx[hh * 64 + wq], c = dy[hh * 64 + wq];
                sx += a; sxx += a * a; sy += c; syy += c * c;
            }
        float cnt = (float)((h1 - h0 + 1) * (w1 - w0 + 1));
        float mx = sx / cnt, my = sy / cnt;
        float var = fmaxf(sxx / cnt - mx * mx, 0.f) + fmaxf(syy / cnt - my * my, 0.f);
        geo[((size_t)b * NDIM + hw) * 8 + k] = 1.f / (1.f + 100.f * var);
    }
}

// -------- 7. softmax over K, refine, confidence blend --------
__global__ void kblend(const float* __restrict__ conf, const float* __restrict__ bex,
                       const float* __restrict__ tlogp, const float* __restrict__ geo,
                       const float* __restrict__ tpos, const float* __restrict__ gwp,
                       float* __restrict__ out) {
    int t = blockIdx.x * 256 + threadIdx.x;
    if (t >= BDIM * NDIM) return;
    float gw = fminf(fmaxf(*gwp, 0.f), 2.f);
    float c[TOPK]; float m = -1e30f;
    #pragma unroll
    for (int k = 0; k < TOPK; k++) { c[k] = tlogp[t * 8 + k] + gw * geo[t * 8 + k]; m = fmaxf(m, c[k]); }
    float s = 0.f, rx = 0.f, ry = 0.f;
    #pragma unroll
    for (int k = 0; k < TOPK; k++) {
        float e = expf(c[k] - m);
        s += e;
        rx += e * tpos[(t * 8 + k) * 2 + 0];
        ry += e * tpos[(t * 8 + k) * 2 + 1];
    }
    float cf = conf[t];
    out[t * 2 + 0] = cf * (rx / s) + (1.f - cf) * bex[t * 2 + 0];
    out[t * 2 + 1] = cf * (ry / s) + (1.f - cf) * bex[t * 2 + 1];
}

extern "C" void kernel_launch(void* const* d_in, const int* in_sizes, int n_in,
                              void* d_out, int out_size, void* d_ws, size_t ws_size,
                              hipStream_t stream) {
    const float* featA = (const float*)d_in[0];
    const float* featB = (const float*)d_in[1];
    const float* posA  = (const float*)d_in[2];
    const float* posB  = (const float*)d_in[3];
    const float* dsp   = (const float*)d_in[4];
    const float* gwp   = (const float*)d_in[5];
    const float* tmpp  = (const float*)d_in[6];

    char* p = (char*)d_ws;
    size_t used = 0;
    auto alloc = [&](size_t bytes) -> void* {
        void* r = (void*)p;
        size_t a = (bytes + 255) & ~(size_t)255;
        p += a; used += a;
        return r;
    };
    __half* E             = (__half*)alloc((size_t)BDIM * NP * LDE * sizeof(__half));   // ~67.3 MB
    unsigned char* E8     = (unsigned char*)alloc((size_t)BDIM * NP * LDE8);            // ~33.7 MB
    __hip_bfloat16* nA    = (__hip_bfloat16*)alloc((size_t)BDIM * NDIM * CDIM * 2);
    __hip_bfloat16* nB    = (__hip_bfloat16*)alloc((size_t)BDIM * NDIM * CDIM * 2);
    float* xu             = (float*)alloc((size_t)BDIM * NP * 4);
    float* w              = (float*)alloc((size_t)BDIM * NP * 4);
    float* cpart          = (float*)alloc((size_t)BDIM * NCH * LDE * 4);
    float* conf           = (float*)alloc((size_t)BDIM * NDIM * 4);
    float* bex            = (float*)alloc((size_t)BDIM * NDIM * 8);
    float* tlogp          = (float*)alloc((size_t)BDIM * NDIM * TOPK * 4);
    float* tpos           = (float*)alloc((size_t)BDIM * NDIM * TOPK * 8);
    float* geo            = (float*)alloc((size_t)BDIM * NDIM * TOPK * 4);
    if (used > ws_size) return;   // need ~106 MB; fail visibly rather than corrupt

    knorm<<<2 * BDIM * NDIM, 64, 0, stream>>>(featA, featB, nA, nB);
    kgemm<<<dim3(NDIM / 128, NDIM / 128, BDIM), 256, 0, stream>>>(nA, nB, E, E8, tmpp);
    kdust<<<(2 * BDIM * NDIM + BDIM + 255) / 256, 256, 0, stream>>>(E, E8, dsp, tmpp, w);
    for (int it = 0; it < 15; ++it) {
        krow<<<(BDIM * NP + 3) / 4, 256, 0, stream>>>(E8, w, xu);
        kcolp<<<dim3(5, NCH, BDIM), 256, 0, stream>>>(E8, xu, cpart);
        kcolf<<<(BDIM * NP + 255) / 256, 256, 0, stream>>>(cpart, w);
    }
    kfinal<<<dim3(NDIM, BDIM), 512, 0, stream>>>(E, xu, w, posB, conf, bex, tlogp, tpos);
    kgeo<<<BDIM * TOPK, 256, 0, stream>>>(tpos, posA, geo);
    kblend<<<(BDIM * NDIM + 255) / 256, 256, 0, stream>>>(conf, bex, tlogp, geo, tpos, gwp, (float*)d_out);
}

// Round 5
// 632.972 us; speedup vs baseline: 1.7479x; 1.0862x over previous
//
#include <hip/hip_runtime.h>
#include <hip/hip_bf16.h>
#include <hip/hip_fp16.h>
#include <math.h>

#define BDIM 2
#define NDIM 4096
#define CDIM 128
#define NP   4097          // NDIM + 1 (dustbin)
#define LDE8 4112          // fp8 row stride (16B-aligned rows)
#define LDC  4104          // colsum stride
#define TOPK 8

typedef __attribute__((ext_vector_type(8))) short short8;
typedef __attribute__((ext_vector_type(4))) float f32x4;
typedef __attribute__((ext_vector_type(2))) float f32x2;

#if defined(__has_builtin)
#if __has_builtin(__builtin_amdgcn_cvt_pk_f32_fp8) && __has_builtin(__builtin_amdgcn_cvt_pk_fp8_f32)
#define HWFP8 1
#endif
#endif

// ---- fp8 e4m3 helpers (positive values only; hw path + manual fallback) ----
__device__ __forceinline__ unsigned char fp8_encode_pos(float x) {
    unsigned u = __float_as_uint(x);
    int e = (int)((u >> 23) & 0xff) - 127;
    if (e < -6) {
        unsigned m = (unsigned)(x * 512.f + 0.5f);
        return (unsigned char)(m > 7 ? 7 : m);
    }
    unsigned mant = u & 0x7fffff;
    unsigned keep = mant >> 20;
    unsigned rest = mant & 0xfffff;
    unsigned rnd = (rest > 0x80000u) || (rest == 0x80000u && (keep & 1));
    keep += rnd;
    if (keep == 8) { keep = 0; e += 1; }
    if (e > 8) { keep = 7; e = 8; }
    return (unsigned char)(((e + 7) << 3) | keep);
}
__device__ __forceinline__ float fp8_decode_pos(unsigned q) {
    unsigned e = (q >> 3) & 0xf, m = q & 7;
    unsigned fn = ((e + 120) << 23) | (m << 20);
    float vs = (float)m * (1.f / 512.f);
    return e ? __uint_as_float(fn) : vs;
}
__device__ __forceinline__ unsigned char enc1(float x) {
#ifdef HWFP8
    int pk = __builtin_amdgcn_cvt_pk_fp8_f32(x, x, 0, false);
    return (unsigned char)(pk & 0xff);
#else
    return fp8_encode_pos(x);
#endif
}
__device__ __forceinline__ void dec4(unsigned v, float* o) {
#ifdef HWFP8
    f32x2 lo = __builtin_amdgcn_cvt_pk_f32_fp8((int)v, false);
    f32x2 hi = __builtin_amdgcn_cvt_pk_f32_fp8((int)v, true);
    o[0] = lo[0]; o[1] = lo[1]; o[2] = hi[0]; o[3] = hi[1];
#else
    o[0] = fp8_decode_pos(v & 0xff); o[1] = fp8_decode_pos((v >> 8) & 0xff);
    o[2] = fp8_decode_pos((v >> 16) & 0xff); o[3] = fp8_decode_pos((v >> 24) & 0xff);
#endif
}

// ---- u32 key sorting (key = 20-bit value | inverted 12-bit index) ----
__device__ __forceinline__ void ceu(unsigned& x, unsigned& y) {
    unsigned hi = x > y ? x : y, lo = x > y ? y : x;
    x = hi; y = lo;
}
__device__ __forceinline__ void sort8u(unsigned* k) {   // descending
    ceu(k[0],k[1]); ceu(k[2],k[3]); ceu(k[4],k[5]); ceu(k[6],k[7]);
    ceu(k[0],k[2]); ceu(k[1],k[3]); ceu(k[4],k[6]); ceu(k[5],k[7]);
    ceu(k[1],k[2]); ceu(k[5],k[6]);
    ceu(k[0],k[4]); ceu(k[1],k[5]); ceu(k[2],k[6]); ceu(k[3],k[7]);
    ceu(k[2],k[4]); ceu(k[3],k[5]);
    ceu(k[1],k[2]); ceu(k[3],k[4]); ceu(k[5],k[6]);
}
__device__ __forceinline__ void merge8u(unsigned* a, const unsigned* b) {
    unsigned c[TOPK];
    #pragma unroll
    for (int s = 0; s < TOPK; s++) c[s] = a[s] > b[7 - s] ? a[s] : b[7 - s];
    #pragma unroll
    for (int k = 4; k >= 1; k >>= 1)
        #pragma unroll
        for (int s = 0; s < TOPK; s++)
            if (!(s & k)) { int s2 = s | k; ceu(c[s], c[s2]); }
    #pragma unroll
    for (int s = 0; s < TOPK; s++) a[s] = c[s];
}

// -------- 1. L2-normalize rows of A and B, write bf16 --------
__global__ __launch_bounds__(64) void knorm(const float* __restrict__ featA,
                                            const float* __restrict__ featB,
                                            __hip_bfloat16* __restrict__ outA,
                                            __hip_bfloat16* __restrict__ outB) {
    int row = blockIdx.x;               // 2*BDIM*NDIM rows
    const float* feat = featA;
    __hip_bfloat16* out = outA;
    if (row >= BDIM * NDIM) { feat = featB; out = outB; row -= BDIM * NDIM; }
    int t = threadIdx.x;
    const float2 x = ((const float2*)(feat + (size_t)row * CDIM))[t];
    float s = x.x * x.x + x.y * x.y;
    #pragma unroll
    for (int o = 32; o > 0; o >>= 1) s += __shfl_xor(s, o);
    float inv = 1.f / fmaxf(sqrtf(s), 1e-12f);
    __hip_bfloat16* o2 = out + (size_t)row * CDIM;
    o2[2 * t]     = __float2bfloat16(x.x * inv);
    o2[2 * t + 1] = __float2bfloat16(x.y * inv);
}

// -------- 2. scores GEMM (MFMA bf16) -> E8 = fp8(exp(clip(scores/temp))) --------
// 1D grid 2048 = 8 XCD-groups x 256; rows i0 land in XCD (blockIdx%8) slice.
__global__ __launch_bounds__(256) void kgemm(const __hip_bfloat16* __restrict__ A16,
                                             const __hip_bfloat16* __restrict__ B16,
                                             unsigned char* __restrict__ E8,
                                             const float* __restrict__ tmpp) {
    int bx = blockIdx.x;
    int g = bx & 7, k = bx >> 3;              // g: XCD group, k: 0..255
    int b = g >> 2, sub = g & 3;
    int i0 = sub * 1024 + (k >> 5) * 128;
    int j0 = (k & 31) * 128;
    int tid = threadIdx.x, lane = tid & 63, wv = tid >> 6;
    int wr = wv >> 1, wc = wv & 1;
    const unsigned short* Ab = (const unsigned short*)A16 + (size_t)b * NDIM * CDIM;
    const unsigned short* Bb = (const unsigned short*)B16 + (size_t)b * NDIM * CDIM;
    int ar = i0 + wr * 64 + (lane & 15);
    int br = j0 + wc * 64 + (lane & 15);
    int koff = (lane >> 4) * 8;
    f32x4 acc[4][4] = {};
    for (int k0 = 0; k0 < CDIM; k0 += 32) {
        short8 a[4], bb[4];
        #pragma unroll
        for (int m = 0; m < 4; m++)
            a[m] = *(const short8*)(Ab + (size_t)(ar + m * 16) * CDIM + k0 + koff);
        #pragma unroll
        for (int n = 0; n < 4; n++)
            bb[n] = *(const short8*)(Bb + (size_t)(br + n * 16) * CDIM + k0 + koff);
        #pragma unroll
        for (int m = 0; m < 4; m++)
            #pragma unroll
            for (int n = 0; n < 4; n++)
                acc[m][n] = __builtin_amdgcn_mfma_f32_16x16x32_bf16(a[m], bb[n], acc[m][n], 0, 0, 0);
    }
    float temp = *tmpp;
    size_t e8base = (size_t)b * NP * LDE8;
    int orow0 = (lane >> 4) * 4;
    int ocol = lane & 15;
    #pragma unroll
    for (int m = 0; m < 4; m++)
        #pragma unroll
        for (int n = 0; n < 4; n++) {
            int gj = j0 + wc * 64 + n * 16 + ocol;
            #pragma unroll
            for (int q = 0; q < 4; q++) {
                int gi = i0 + wr * 64 + m * 16 + orow0 + q;
                float s = acc[m][n][q] / temp;
                if (s != s) s = 0.f;
                s = fminf(fmaxf(s, -50.f), 50.f);
                float e = fminf(expf(s), 440.f);
                E8[e8base + (size_t)gi * LDE8 + gj] = enc1(e);
            }
        }
}

// -------- 3. dustbin row/col/corner + init w + zero colsum --------
__global__ void kdust(unsigned char* __restrict__ E8, const float* __restrict__ dsp,
                      const float* __restrict__ tmpp, float* __restrict__ w,
                      float* __restrict__ colsum) {
    int t = blockIdx.x * 256 + threadIdx.x;
    float temp = fminf(fmaxf(*tmpp, 0.2f), 10.f);
    float ds = fminf(fmaxf((*dsp) / temp, -50.f), 50.f);
    unsigned char e8 = enc1(fminf(expf(ds), 440.f));
    if (t < BDIM * NDIM) {
        int b = t / NDIM, j = t % NDIM;
        E8[((size_t)b * NP + NDIM) * LDE8 + j] = e8;         // dust row
    } else if (t < 2 * BDIM * NDIM) {
        int u2 = t - BDIM * NDIM;
        int b = u2 / NDIM, i = u2 % NDIM;
        E8[((size_t)b * NP + i) * LDE8 + NDIM] = e8;         // dust col
    } else if (t < 2 * BDIM * NDIM + BDIM) {
        int b = t - 2 * BDIM * NDIM;
        E8[((size_t)b * NP + NDIM) * LDE8 + NDIM] = enc1(1.f);  // corner
    }
    if (t < BDIM * NP) w[t] = 1.f;
    if (t < BDIM * LDC) colsum[t] = 0.f;
}

// -------- 4a. row pass: one WAVE per row, XCD-pinned --------
__global__ __launch_bounds__(256) void krow(const unsigned char* __restrict__ E8,
                                            const float* __restrict__ w,
                                            float* __restrict__ xu) {
    int bx = blockIdx.x;
    int g = bx & 7, k = bx >> 3;             // k: 0..256
    int b = g >> 2, sub = g & 3;
    int i = sub * 1024 + k * 4 + (threadIdx.x >> 6);
    int iend = (sub == 3) ? NP : (sub + 1) * 1024;
    if (i >= iend) return;
    int lane = threadIdx.x & 63;
    size_t rid = (size_t)b * NP + i;
    const unsigned char* rowb = E8 + rid * LDE8;
    const uint4* row = (const uint4*)rowb;
    const float* wb = w + (size_t)b * NP;
    float acc = 0.f;
    #pragma unroll
    for (int it = 0; it < 4; it++) {
        int c = lane + 64 * it;              // 16-byte chunk -> cols c*16..c*16+15
        uint4 v = row[c];
        const float4* wp = (const float4*)(wb + c * 16);
        float4 wa = wp[0], wbv = wp[1], wcv = wp[2], wdv = wp[3];
        float d[16];
        dec4(v.x, d); dec4(v.y, d + 4); dec4(v.z, d + 8); dec4(v.w, d + 12);
        acc += d[0] * wa.x + d[1] * wa.y + d[2] * wa.z + d[3] * wa.w;
        acc += d[4] * wbv.x + d[5] * wbv.y + d[6] * wbv.z + d[7] * wbv.w;
        acc += d[8] * wcv.x + d[9] * wcv.y + d[10] * wcv.z + d[11] * wcv.w;
        acc += d[12] * wdv.x + d[13] * wdv.y + d[14] * wdv.z + d[15] * wdv.w;
    }
    if (lane == 0) {
        float dd[4];
        dec4((unsigned)rowb[NDIM], dd);
        acc += dd[0] * wb[NDIM];
    }
    #pragma unroll
    for (int o = 32; o > 0; o >>= 1) acc += __shfl_xor(acc, o);
    if (lane == 0) {
        float mu = (i == NDIM) ? 0.5f : (1.f / 8192.f);
        xu[rid] = mu / fmaxf(acc, 1e-35f);
    }
}

// -------- 4b. column pass: XCD-pinned chunks, atomic accumulate into colsum --------
__global__ __launch_bounds__(256) void kcolp(const unsigned char* __restrict__ E8,
                                             const float* __restrict__ xu,
                                             float* __restrict__ colsum) {
    int bx = blockIdx.x;
    int g = bx & 7, k = bx >> 3;             // k: 0..84
    int b = g >> 2, sub = g & 3;
    int nch = (sub == 3) ? 17 : 16;
    if (k >= nch * 5) return;
    int ch = sub * 16 + k / 5, pan = k % 5;
    int j = pan * 1024 + threadIdx.x * 4;
    if (j >= NP) return;
    int r0 = ch * 64, r1 = min(r0 + 64, NP);
    const unsigned char* base = E8 + (size_t)b * NP * LDE8 + j;
    const float* xb = xu + (size_t)b * NP;
    float a0 = 0, a1 = 0, a2 = 0, a3 = 0, c0 = 0, c1 = 0, c2 = 0, c3 = 0;
    int i = r0;
    for (; i + 1 < r1; i += 2) {
        unsigned v0 = *(const unsigned*)(base + (size_t)i * LDE8);
        unsigned v1 = *(const unsigned*)(base + (size_t)(i + 1) * LDE8);
        float x0 = xb[i], x1 = xb[i + 1];
        float d0[4], d1[4];
        dec4(v0, d0); dec4(v1, d1);
        a0 += d0[0] * x0; a1 += d0[1] * x0; a2 += d0[2] * x0; a3 += d0[3] * x0;
        c0 += d1[0] * x1; c1 += d1[1] * x1; c2 += d1[2] * x1; c3 += d1[3] * x1;
    }
    if (i < r1) {
        unsigned v0 = *(const unsigned*)(base + (size_t)i * LDE8);
        float x0 = xb[i];
        float d0[4];
        dec4(v0, d0);
        a0 += d0[0] * x0; a1 += d0[1] * x0; a2 += d0[2] * x0; a3 += d0[3] * x0;
    }
    float* cs = colsum + (size_t)b * LDC;
    atomicAdd(cs + j, a0 + c0);
    if (j + 1 < NP) atomicAdd(cs + j + 1, a1 + c1);
    if (j + 2 < NP) atomicAdd(cs + j + 2, a2 + c2);
    if (j + 3 < NP) atomicAdd(cs + j + 3, a3 + c3);
}

// -------- 4c. finish: w_j = nu_j / colsum_j ; reset colsum for next iter --------
__global__ void kcolf(float* __restrict__ colsum, float* __restrict__ w) {
    int t = blockIdx.x * 256 + threadIdx.x;
    if (t >= BDIM * NP) return;
    int b = t / NP, j = t - b * NP;
    float s = colsum[(size_t)b * LDC + j];
    colsum[(size_t)b * LDC + j] = 0.f;
    float nu = (j == NDIM) ? 0.5f : (1.f / 8192.f);
    w[t] = nu / fmaxf(s, 1e-35f);
}

// -------- 5. final row pass (fp8): u32 keys, sort8 + LDS tree merge, XCD-pinned --------
__global__ __launch_bounds__(512) void kfinal(const unsigned char* __restrict__ E8,
                                              const float* __restrict__ xu,
                                              const float* __restrict__ w,
                                              const float* __restrict__ posB,
                                              float* __restrict__ conf,
                                              float* __restrict__ bex,
                                              float* __restrict__ tlogp,
                                              float* __restrict__ tpos) {
    int bx = blockIdx.x;
    int g = bx & 7, k = bx >> 3;             // k: 0..1023
    int b = g >> 2;
    int i = (g & 3) * 1024 + k;              // i < 4096
    int tid = threadIdx.x, lane = tid & 63, wv = tid >> 6;   // 8 waves
    size_t rid = (size_t)b * NP + i;
    const unsigned char* rowb = E8 + rid * LDE8;
    const float* wb = w + (size_t)b * NP;
    const float2* pb = (const float2*)posB + (size_t)b * NDIM;
    float eu = xu[rid];
    int j = tid * 8;
    uint2 v = *(const uint2*)(rowb + j);
    float d[8];
    dec4(v.x, d); dec4(v.y, d + 4);
    float4 w0 = ((const float4*)(wb + j))[0];
    float4 w1 = ((const float4*)(wb + j))[1];
    float wj[8] = {w0.x, w0.y, w0.z, w0.w, w1.x, w1.y, w1.z, w1.w};
    float rs = 0.f, px = 0.f, py = 0.f;
    unsigned kk[TOPK];
    #pragma unroll
    for (int e = 0; e < 8; e++) {
        int jj = j + e;
        float p = d[e] * wj[e];
        float2 q = pb[jj];
        rs += p; px += p * q.x; py += p * q.y;
        kk[e] = (__float_as_uint(p) & 0xFFFFF000u) | (unsigned)(4095 - jj);
    }
    sort8u(kk);
    #pragma unroll
    for (int o = 32; o > 0; o >>= 1) {
        rs += __shfl_xor(rs, o); px += __shfl_xor(px, o); py += __shfl_xor(py, o);
    }
    __shared__ float redv[3][8];
    __shared__ unsigned lk[512 * 9];
    __shared__ unsigned fin[TOPK];
    if (lane == 0) { redv[0][wv] = rs; redv[1][wv] = px; redv[2][wv] = py; }
    #pragma unroll
    for (int s = 0; s < TOPK; s++) lk[tid * 9 + s] = kk[s];
    __syncthreads();
    for (int step = 1; step < 512; step <<= 1) {
        if ((tid & (2 * step - 1)) == 0) {
            unsigned pk[TOPK];
            int o = (tid + step) * 9;
            #pragma unroll
            for (int s = 0; s < TOPK; s++) pk[s] = lk[o + s];
            merge8u(kk, pk);
            if (step < 256) {
                #pragma unroll
                for (int s = 0; s < TOPK; s++) lk[tid * 9 + s] = kk[s];
            }
        }
        __syncthreads();
    }
    if (tid == 0) {
        #pragma unroll
        for (int s = 0; s < TOPK; s++) fin[s] = kk[s];
    }
    __syncthreads();
    size_t rowid = (size_t)b * NDIM + i;
    if (tid < TOPK) {
        unsigned key = fin[tid];
        int jj = 4095 - (int)(key & 0xFFFu);
        float val = __uint_as_float(key & 0xFFFFF000u) * eu;
        tlogp[rowid * 8 + tid] = logf(fmaxf(val, 1e-38f));
        float2 q = pb[jj];
        tpos[(rowid * 8 + tid) * 2 + 0] = q.x;
        tpos[(rowid * 8 + tid) * 2 + 1] = q.y;
    }
    if (tid == 0) {
        float rst = 0, pxt = 0, pyt = 0;
        #pragma unroll
        for (int q = 0; q < 8; q++) { rst += redv[0][q]; pxt += redv[1][q]; pyt += redv[2][q]; }
        float rm = fmaxf(rst * eu, 1e-8f);
        float valid = fminf(rm * (float)(2 * NDIM), 1.f);
        float top1 = __uint_as_float(fin[0] & 0xFFFFF000u) * eu;
        float top2 = __uint_as_float(fin[1] & 0xFFFFF000u) * eu;
        float pr = fminf(fmaxf(top1 / rm, 0.f), 1.f);
        float pm = fminf(fmaxf((top1 - top2) / rm, 0.f), 1.f);
        conf[rowid] = fminf(fmaxf((0.6f * pr + 0.4f * pm) * valid, 0.f), 1.f);
        bex[rowid * 2 + 0] = pxt * eu / rm;
        bex[rowid * 2 + 1] = pyt * eu / rm;
    }
}

// -------- 6. geometric validation: 7x7 avg-pool (count_include_pad=False) --------
__global__ __launch_bounds__(256) void kgeo(const float* __restrict__ tpos,
                                            const float* __restrict__ posA,
                                            float* __restrict__ geo) {
    int b = blockIdx.x >> 3, k = blockIdx.x & 7;
    __shared__ float dx[4096], dy[4096];
    for (int hw = threadIdx.x; hw < 4096; hw += 256) {
        float2 pa = ((const float2*)posA)[(size_t)b * NDIM + hw];
        const float* tp = tpos + (((size_t)b * NDIM + hw) * 8 + k) * 2;
        dx[hw] = tp[0] - pa.x;
        dy[hw] = tp[1] - pa.y;
    }
    __syncthreads();
    for (int hw = threadIdx.x; hw < 4096; hw += 256) {
        int h = hw >> 6, ww = hw & 63;
        int h0 = max(h - 3, 0), h1 = min(h + 3, 63);
        int w0 = max(ww - 3, 0), w1 = min(ww + 3, 63);
        float sx = 0, sy = 0, sxx = 0, syy = 0;
        for (int hh = h0; hh <= h1; hh++)
            for (int wq = w0; wq <= w1; wq++) {
                float a = dx[hh * 64 + wq], c = dy[hh * 64 + wq];
                sx += a; sxx += a * a; sy += c; syy += c * c;
            }
        float cnt = (float)((h1 - h0 + 1) * (w1 - w0 + 1));
        float mx = sx / cnt, my = sy / cnt;
        float var = fmaxf(sxx / cnt - mx * mx, 0.f) + fmaxf(syy / cnt - my * my, 0.f);
        geo[((size_t)b * NDIM + hw) * 8 + k] = 1.f / (1.f + 100.f * var);
    }
}

// -------- 7. softmax over K, refine, confidence blend --------
__global__ void kblend(const float* __restrict__ conf, const float* __restrict__ bex,
                       const float* __restrict__ tlogp, const float* __restrict__ geo,
                       const float* __restrict__ tpos, const float* __restrict__ gwp,
                       float* __restrict__ out) {
    int t = blockIdx.x * 256 + threadIdx.x;
    if (t >= BDIM * NDIM) return;
    float gw = fminf(fmaxf(*gwp, 0.f), 2.f);
    float c[TOPK]; float m = -1e30f;
    #pragma unroll
    for (int k = 0; k < TOPK; k++) { c[k] = tlogp[t * 8 + k] + gw * geo[t * 8 + k]; m = fmaxf(m, c[k]); }
    float s = 0.f, rx = 0.f, ry = 0.f;
    #pragma unroll
    for (int k = 0; k < TOPK; k++) {
        float e = expf(c[k] - m);
        s += e;
        rx += e * tpos[(t * 8 + k) * 2 + 0];
        ry += e * tpos[(t * 8 + k) * 2 + 1];
    }
    float cf = conf[t];
    out[t * 2 + 0] = cf * (rx / s) + (1.f - cf) * bex[t * 2 + 0];
    out[t * 2 + 1] = cf * (ry / s) + (1.f - cf) * bex[t * 2 + 1];
}

extern "C" void kernel_launch(void* const* d_in, const int* in_sizes, int n_in,
                              void* d_out, int out_size, void* d_ws, size_t ws_size,
                              hipStream_t stream) {
    const float* featA = (const float*)d_in[0];
    const float* featB = (const float*)d_in[1];
    const float* posA  = (const float*)d_in[2];
    const float* posB  = (const float*)d_in[3];
    const float* dsp   = (const float*)d_in[4];
    const float* gwp   = (const float*)d_in[5];
    const float* tmpp  = (const float*)d_in[6];

    char* p = (char*)d_ws;
    size_t used = 0;
    auto alloc = [&](size_t bytes) -> void* {
        void* r = (void*)p;
        size_t a = (bytes + 255) & ~(size_t)255;
        p += a; used += a;
        return r;
    };
    unsigned char* E8     = (unsigned char*)alloc((size_t)BDIM * NP * LDE8);            // ~33.7 MB
    __hip_bfloat16* nA    = (__hip_bfloat16*)alloc((size_t)BDIM * NDIM * CDIM * 2);
    __hip_bfloat16* nB    = (__hip_bfloat16*)alloc((size_t)BDIM * NDIM * CDIM * 2);
    float* xu             = (float*)alloc((size_t)BDIM * NP * 4);
    float* w              = (float*)alloc((size_t)BDIM * NP * 4);
    float* colsum         = (float*)alloc((size_t)BDIM * LDC * 4);
    float* conf           = (float*)alloc((size_t)BDIM * NDIM * 4);
    float* bex            = (float*)alloc((size_t)BDIM * NDIM * 8);
    float* tlogp          = (float*)alloc((size_t)BDIM * NDIM * TOPK * 4);
    float* tpos           = (float*)alloc((size_t)BDIM * NDIM * TOPK * 8);
    float* geo            = (float*)alloc((size_t)BDIM * NDIM * TOPK * 4);
    if (used > ws_size) return;   // need ~40 MB; fail visibly rather than corrupt

    knorm<<<2 * BDIM * NDIM, 64, 0, stream>>>(featA, featB, nA, nB);
    kgemm<<<2048, 256, 0, stream>>>(nA, nB, E8, tmpp);
    kdust<<<(2 * BDIM * NDIM + BDIM + 255) / 256, 256, 0, stream>>>(E8, dsp, tmpp, w, colsum);
    for (int it = 0; it < 15; ++it) {
        krow<<<8 * 257, 256, 0, stream>>>(E8, w, xu);
        kcolp<<<8 * 85, 256, 0, stream>>>(E8, xu, colsum);
        kcolf<<<(BDIM * NP + 255) / 256, 256, 0, stream>>>(colsum, w);
    }
    kfinal<<<8192, 512, 0, stream>>>(E8, xu, w, posB, conf, bex, tlogp, tpos);
    kgeo<<<BDIM * TOPK, 256, 0, stream>>>(tpos, posA, geo);
    kblend<<<(BDIM * NDIM + 255) / 256, 256, 0, stream>>>(conf, bex, tlogp, geo, tpos, gwp, (float*)d_out);
}